// Round 1
// baseline (3636.535 us; speedup 1.0000x reference)
//
#include <hip/hip_runtime.h>

#define N_NODES 50000
#define N_EDGES 600000
#define HID 128
#define N_GRAPHS 512
#define BN_EPS 1e-5f

// ---------------------------------------------------------------------------
// degree (in-edge count per dst node)
// ---------------------------------------------------------------------------
__global__ void deg_kernel(const int* __restrict__ dst, float* __restrict__ deg, int nE) {
    int e = blockIdx.x * blockDim.x + threadIdx.x;
    if (e < nE) atomicAdd(&deg[dst[e]], 1.0f);
}

__global__ void inv_deg_kernel(float* __restrict__ deg, int n) {
    int i = blockIdx.x * blockDim.x + threadIdx.x;
    if (i < n) deg[i] = 1.0f / fmaxf(deg[i], 1.0f);
}

// ---------------------------------------------------------------------------
// scatter-add: agg[dst[e], :] += feat[src[e], :]
// 32 lanes per edge, float4 per lane (128 feats)
// ---------------------------------------------------------------------------
__global__ void scatter_add_kernel(const float* __restrict__ feat,
                                   const int* __restrict__ src,
                                   const int* __restrict__ dst,
                                   float* __restrict__ agg, int nE) {
    int gid = blockIdx.x * blockDim.x + threadIdx.x;
    int e = gid >> 5;
    int lane = gid & 31;
    if (e >= nE) return;
    int s = src[e];
    int d = dst[e];
    float4 v = ((const float4*)(feat + (size_t)s * HID))[lane];
    float* dp = agg + (size_t)d * HID + lane * 4;
    atomicAdd(dp + 0, v.x);
    atomicAdd(dp + 1, v.y);
    atomicAdd(dp + 2, v.z);
    atomicAdd(dp + 3, v.w);
}

// ---------------------------------------------------------------------------
// GEMM, N = K = 128 (MODE 2: K = 256 via two phases).
// MODE 0: C = relu((A + B) @ W1 + bias)          (GIN layer 1)
// MODE 1: C = A @ W1 + bias                      (GIN layer 2, pre-BN)
// MODE 2: C = (A*scale[i]) @ W1 + B @ W2 + bias  (SAGE, pre-BN)
// Tile: 64 rows x 128 cols per 256-thread block; per-thread 8 rows x 4 cols.
// ---------------------------------------------------------------------------
template<int MODE>
__global__ __launch_bounds__(256) void gemm128_kernel(
    const float* __restrict__ A, const float* __restrict__ B,
    const float* __restrict__ W1, const float* __restrict__ W2,
    const float* __restrict__ bias, const float* __restrict__ scale,
    float* __restrict__ C, int M)
{
    __shared__ float As[64 * 36];     // 64 rows x 32 k, pad to 36 (16B-aligned rows)
    __shared__ float Ws[32 * 128];    // 32 k x 128 cols

    const int t = threadIdx.x;
    const int colg = t & 31;          // cols 4*colg .. 4*colg+3
    const int rowg = t >> 5;          // rows rowg*8 .. rowg*8+7
    const int row0 = blockIdx.x * 64;

    float acc[8][4];
#pragma unroll
    for (int j = 0; j < 8; j++)
#pragma unroll
        for (int c = 0; c < 4; c++) acc[j][c] = 0.f;

    const int nphase = (MODE == 2) ? 2 : 1;
    for (int phase = 0; phase < nphase; phase++) {
        const float* Ap = (MODE == 2 && phase == 1) ? B : A;
        const float* Wp = (MODE == 2 && phase == 1) ? W2 : W1;
        for (int kc = 0; kc < 128; kc += 32) {
            // stage A chunk: 64 rows x 32 floats = 512 float4, 2 per thread
#pragma unroll
            for (int i = 0; i < 2; i++) {
                int f4 = t + i * 256;
                int r = f4 >> 3;           // 8 float4 per row
                int c4 = f4 & 7;
                int grow = row0 + r;
                float4 v = make_float4(0.f, 0.f, 0.f, 0.f);
                if (grow < M) {
                    v = *(const float4*)(Ap + (size_t)grow * 128 + kc + c4 * 4);
                    if (MODE == 0) {
                        float4 v2 = *(const float4*)(B + (size_t)grow * 128 + kc + c4 * 4);
                        v.x += v2.x; v.y += v2.y; v.z += v2.z; v.w += v2.w;
                    }
                    if (MODE == 2 && phase == 0) {
                        float sc = scale[grow];
                        v.x *= sc; v.y *= sc; v.z *= sc; v.w *= sc;
                    }
                }
                *(float4*)(As + r * 36 + c4 * 4) = v;
            }
            // stage W chunk: 32 rows x 128 cols = 1024 float4, 4 per thread
#pragma unroll
            for (int i = 0; i < 4; i++) {
                int f4 = t + i * 256;
                int wr = f4 >> 5;          // 32 float4 per row
                int wc = f4 & 31;
                *(float4*)(Ws + wr * 128 + wc * 4) =
                    *(const float4*)(Wp + (size_t)(kc + wr) * 128 + wc * 4);
            }
            __syncthreads();
#pragma unroll
            for (int k = 0; k < 32; k++) {
                float4 w = *(const float4*)(Ws + k * 128 + colg * 4);
#pragma unroll
                for (int j = 0; j < 8; j++) {
                    float a = As[(rowg * 8 + j) * 36 + k];
                    acc[j][0] += a * w.x;
                    acc[j][1] += a * w.y;
                    acc[j][2] += a * w.z;
                    acc[j][3] += a * w.w;
                }
            }
            __syncthreads();
        }
    }

    float4 bs = *(const float4*)(bias + colg * 4);
#pragma unroll
    for (int j = 0; j < 8; j++) {
        int grow = row0 + rowg * 8 + j;
        if (grow >= M) continue;
        float4 o;
        o.x = acc[j][0] + bs.x;
        o.y = acc[j][1] + bs.y;
        o.z = acc[j][2] + bs.z;
        o.w = acc[j][3] + bs.w;
        if (MODE == 0) {
            o.x = fmaxf(o.x, 0.f); o.y = fmaxf(o.y, 0.f);
            o.z = fmaxf(o.z, 0.f); o.w = fmaxf(o.w, 0.f);
        }
        *(float4*)(C + (size_t)grow * 128 + colg * 4) = o;
    }
}

// ---------------------------------------------------------------------------
// BatchNorm: column sums / sumsq over n rows (atomics into stats[0:128]=sum,
// stats[128:256]=sumsq), then fused apply + relu.
// ---------------------------------------------------------------------------
__global__ void bn_stats_kernel(const float* __restrict__ h, float* __restrict__ stats, int n) {
    int col = threadIdx.x & 127;
    int half = threadIdx.x >> 7;   // 256 threads -> 2 rows per iteration
    float s = 0.f, s2 = 0.f;
    for (int i = blockIdx.x * 2 + half; i < n; i += gridDim.x * 2) {
        float v = h[(size_t)i * 128 + col];
        s += v;
        s2 += v * v;
    }
    __shared__ float ls[256], ls2[256];
    ls[threadIdx.x] = s;
    ls2[threadIdx.x] = s2;
    __syncthreads();
    if (threadIdx.x < 128) {
        atomicAdd(&stats[col], ls[threadIdx.x] + ls[threadIdx.x + 128]);
        atomicAdd(&stats[128 + col], ls2[threadIdx.x] + ls2[threadIdx.x + 128]);
    }
}

__global__ void bn_apply_relu_kernel(float* __restrict__ h, const float* __restrict__ stats,
                                     const float* __restrict__ gamma,
                                     const float* __restrict__ beta, int n) {
    int gid = blockIdx.x * blockDim.x + threadIdx.x;
    int i = gid >> 5;
    int c4 = gid & 31;
    if (i >= n) return;
    int col = c4 * 4;
    float inv_n = 1.0f / (float)n;
    float4 v = *(float4*)(h + (size_t)i * 128 + col);
    float o[4] = {v.x, v.y, v.z, v.w};
#pragma unroll
    for (int cc = 0; cc < 4; cc++) {
        float mu = stats[col + cc] * inv_n;
        float var = stats[128 + col + cc] * inv_n - mu * mu;
        float rs = rsqrtf(var + BN_EPS);
        o[cc] = fmaxf(gamma[col + cc] * (o[cc] - mu) * rs + beta[col + cc], 0.f);
    }
    *(float4*)(h + (size_t)i * 128 + col) = make_float4(o[0], o[1], o[2], o[3]);
}

// ---------------------------------------------------------------------------
// global mean pool
// ---------------------------------------------------------------------------
__global__ void pool_count_kernel(const int* __restrict__ batch, float* __restrict__ counts, int n) {
    int i = blockIdx.x * blockDim.x + threadIdx.x;
    if (i < n) atomicAdd(&counts[batch[i]], 1.0f);
}

__global__ void pool_sum_kernel(const float* __restrict__ h, const int* __restrict__ batch,
                                float* __restrict__ out, int n) {
    int gid = blockIdx.x * blockDim.x + threadIdx.x;
    int i = gid >> 5;
    int c4 = gid & 31;
    if (i >= n) return;
    int g = batch[i];
    float4 v = *(const float4*)(h + (size_t)i * 128 + c4 * 4);
    float* dp = out + (size_t)g * 128 + c4 * 4;
    atomicAdd(dp + 0, v.x);
    atomicAdd(dp + 1, v.y);
    atomicAdd(dp + 2, v.z);
    atomicAdd(dp + 3, v.w);
}

__global__ void pool_div_kernel(float* __restrict__ out, const float* __restrict__ counts) {
    int gid = blockIdx.x * blockDim.x + threadIdx.x;
    if (gid >= N_GRAPHS * HID) return;
    int g = gid >> 7;
    out[gid] /= fmaxf(counts[g], 1.0f);
}

// ---------------------------------------------------------------------------
extern "C" void kernel_launch(void* const* d_in, const int* in_sizes, int n_in,
                              void* d_out, int out_size, void* d_ws, size_t ws_size,
                              hipStream_t stream) {
    const float* x    = (const float*)d_in[0];
    const int*   ei   = (const int*)d_in[1];
    const int*   src  = ei;               // edge_index[0]
    const int*   dst  = ei + N_EDGES;     // edge_index[1]
    const int*   batch = (const int*)d_in[2];
    const float* gw1  = (const float*)d_in[3];
    const float* gb1  = (const float*)d_in[4];
    const float* gw2  = (const float*)d_in[5];
    const float* gb2  = (const float*)d_in[6];
    const float* swl  = (const float*)d_in[7];   // [2,128,128]
    const float* sbl  = (const float*)d_in[8];   // [2,128]
    const float* swr  = (const float*)d_in[9];   // [2,128,128]
    const float* bng  = (const float*)d_in[10];  // [3,128]
    const float* bnb  = (const float*)d_in[11];  // [3,128]
    float* out = (float*)d_out;

    // workspace layout (floats): agg 6.4M | hA 6.4M | hB 6.4M | deg 50k | stats 256 | counts 512
    // total ~77 MB
    float* ws    = (float*)d_ws;
    float* agg   = ws;
    float* hA    = ws + 6400000;
    float* hB    = ws + 12800000;
    float* deg   = ws + 19200000;
    float* stats = ws + 19250000;
    float* counts = ws + 19250256;

    const size_t feat_bytes = (size_t)N_NODES * HID * sizeof(float);
    const int scat_blocks = (N_EDGES * 32) / 256;       // exact
    const int elem_blocks = (N_NODES * 32 + 255) / 256; // per-node x 32 lanes
    const int gemm_blocks = (N_NODES + 63) / 64;

    // ---- degrees ----
    hipMemsetAsync(deg, 0, N_NODES * sizeof(float), stream);
    deg_kernel<<<(N_EDGES + 255) / 256, 256, 0, stream>>>(dst, deg, N_EDGES);
    inv_deg_kernel<<<(N_NODES + 255) / 256, 256, 0, stream>>>(deg, N_NODES);

    // ---- GIN: agg = scatter(x); hA = relu((x+agg)@W1+b1); hB = hA@W2+b2 ----
    hipMemsetAsync(agg, 0, feat_bytes, stream);
    scatter_add_kernel<<<scat_blocks, 256, 0, stream>>>(x, src, dst, agg, N_EDGES);
    gemm128_kernel<0><<<gemm_blocks, 256, 0, stream>>>(x, agg, gw1, nullptr, gb1, nullptr, hA, N_NODES);
    gemm128_kernel<1><<<gemm_blocks, 256, 0, stream>>>(hA, nullptr, gw2, nullptr, gb2, nullptr, hB, N_NODES);
    hipMemsetAsync(stats, 0, 256 * sizeof(float), stream);
    bn_stats_kernel<<<256, 256, 0, stream>>>(hB, stats, N_NODES);
    bn_apply_relu_kernel<<<elem_blocks, 256, 0, stream>>>(hB, stats, bng + 0 * HID, bnb + 0 * HID, N_NODES);
    // h = hB

    // ---- SAGE layer 0: hA = (agg*inv_deg)@wl0 + hB@wr0 + bl0 ----
    hipMemsetAsync(agg, 0, feat_bytes, stream);
    scatter_add_kernel<<<scat_blocks, 256, 0, stream>>>(hB, src, dst, agg, N_EDGES);
    gemm128_kernel<2><<<gemm_blocks, 256, 0, stream>>>(agg, hB, swl + 0 * HID * HID, swr + 0 * HID * HID,
                                                       sbl + 0 * HID, deg, hA, N_NODES);
    hipMemsetAsync(stats, 0, 256 * sizeof(float), stream);
    bn_stats_kernel<<<256, 256, 0, stream>>>(hA, stats, N_NODES);
    bn_apply_relu_kernel<<<elem_blocks, 256, 0, stream>>>(hA, stats, bng + 1 * HID, bnb + 1 * HID, N_NODES);
    // h = hA

    // ---- SAGE layer 1: hB = (agg*inv_deg)@wl1 + hA@wr1 + bl1 ----
    hipMemsetAsync(agg, 0, feat_bytes, stream);
    scatter_add_kernel<<<scat_blocks, 256, 0, stream>>>(hA, src, dst, agg, N_EDGES);
    gemm128_kernel<2><<<gemm_blocks, 256, 0, stream>>>(agg, hA, swl + 1 * HID * HID, swr + 1 * HID * HID,
                                                       sbl + 1 * HID, deg, hB, N_NODES);
    hipMemsetAsync(stats, 0, 256 * sizeof(float), stream);
    bn_stats_kernel<<<256, 256, 0, stream>>>(hB, stats, N_NODES);
    bn_apply_relu_kernel<<<elem_blocks, 256, 0, stream>>>(hB, stats, bng + 2 * HID, bnb + 2 * HID, N_NODES);
    // h = hB

    // ---- global mean pool ----
    hipMemsetAsync(out, 0, (size_t)N_GRAPHS * HID * sizeof(float), stream);
    hipMemsetAsync(counts, 0, N_GRAPHS * sizeof(float), stream);
    pool_count_kernel<<<(N_NODES + 255) / 256, 256, 0, stream>>>(batch, counts, N_NODES);
    pool_sum_kernel<<<elem_blocks, 256, 0, stream>>>(hB, batch, out, N_NODES);
    pool_div_kernel<<<(N_GRAPHS * HID + 255) / 256, 256, 0, stream>>>(out, counts);
}

// Round 2
// 722.326 us; speedup vs baseline: 5.0345x; 5.0345x over previous
//
#include <hip/hip_runtime.h>

#define N_NODES 50000
#define N_EDGES 600000
#define HID 128
#define N_GRAPHS 512
#define BN_EPS 1e-5f

// ---------------------------------------------------------------------------
// CSR build: degree count -> exclusive scan -> cursor copy -> fill
// ---------------------------------------------------------------------------
__global__ void deg_count_kernel(const int* __restrict__ dst, int* __restrict__ deg, int nE) {
    int e = blockIdx.x * blockDim.x + threadIdx.x;
    if (e < nE) atomicAdd(&deg[dst[e]], 1);
}

// single-block exclusive scan over n ints (n up to ~64k), 1024 threads
__global__ __launch_bounds__(1024) void scan_kernel(const int* __restrict__ deg,
                                                    int* __restrict__ row_off, int n) {
    __shared__ int tmp[1024];
    __shared__ int carry;
    if (threadIdx.x == 0) carry = 0;
    __syncthreads();
    for (int base = 0; base < n; base += 1024) {
        int i = base + threadIdx.x;
        int v = (i < n) ? deg[i] : 0;
        tmp[threadIdx.x] = v;
        __syncthreads();
        for (int off = 1; off < 1024; off <<= 1) {
            int t = (threadIdx.x >= off) ? tmp[threadIdx.x - off] : 0;
            __syncthreads();
            tmp[threadIdx.x] += t;
            __syncthreads();
        }
        if (i < n) row_off[i] = carry + tmp[threadIdx.x] - v;  // exclusive
        __syncthreads();
        if (threadIdx.x == 1023) carry += tmp[1023];
        __syncthreads();
    }
    if (threadIdx.x == 0) row_off[n] = carry;
}

__global__ void copy_int_kernel(const int* __restrict__ a, int* __restrict__ b, int n) {
    int i = blockIdx.x * blockDim.x + threadIdx.x;
    if (i < n) b[i] = a[i];
}

__global__ void csr_fill_kernel(const int* __restrict__ src, const int* __restrict__ dst,
                                int* __restrict__ cursor, int* __restrict__ csr_src, int nE) {
    int e = blockIdx.x * blockDim.x + threadIdx.x;
    if (e < nE) {
        int pos = atomicAdd(&cursor[dst[e]], 1);
        csr_src[pos] = src[e];
    }
}

__global__ void inv_deg_kernel(const int* __restrict__ row_off, float* __restrict__ inv_deg, int n) {
    int i = blockIdx.x * blockDim.x + threadIdx.x;
    if (i < n) {
        int d = row_off[i + 1] - row_off[i];
        inv_deg[i] = 1.0f / fmaxf((float)d, 1.0f);
    }
}

// ---------------------------------------------------------------------------
// gather-based aggregation: agg[i,:] = sum_{e in CSR[i]} feat[csr_src[e],:]
// half-wave (32 lanes x float4) per node
// ---------------------------------------------------------------------------
__global__ void csr_aggregate_kernel(const float* __restrict__ feat,
                                     const int* __restrict__ row_off,
                                     const int* __restrict__ csr_src,
                                     float* __restrict__ agg, int n) {
    int gid = blockIdx.x * blockDim.x + threadIdx.x;
    int node = gid >> 5;
    int lane = gid & 31;
    if (node >= n) return;
    int beg = row_off[node];
    int end = row_off[node + 1];
    float4 acc = make_float4(0.f, 0.f, 0.f, 0.f);
    int e = beg;
    for (; e + 1 < end; e += 2) {
        int s0 = csr_src[e];
        int s1 = csr_src[e + 1];
        float4 v0 = ((const float4*)(feat + (size_t)s0 * HID))[lane];
        float4 v1 = ((const float4*)(feat + (size_t)s1 * HID))[lane];
        acc.x += v0.x + v1.x;
        acc.y += v0.y + v1.y;
        acc.z += v0.z + v1.z;
        acc.w += v0.w + v1.w;
    }
    if (e < end) {
        int s0 = csr_src[e];
        float4 v0 = ((const float4*)(feat + (size_t)s0 * HID))[lane];
        acc.x += v0.x; acc.y += v0.y; acc.z += v0.z; acc.w += v0.w;
    }
    ((float4*)(agg + (size_t)node * HID))[lane] = acc;
}

// ---------------------------------------------------------------------------
// GEMM, N = K = 128 (MODE 2: K = 256 via two phases).
// MODE 0: C = relu((A + B) @ W1 + bias)          (GIN layer 1)
// MODE 1: C = A @ W1 + bias                      (GIN layer 2, pre-BN)
// MODE 2: C = (A*scale[i]) @ W1 + B @ W2 + bias  (SAGE, pre-BN)
// ---------------------------------------------------------------------------
template<int MODE>
__global__ __launch_bounds__(256) void gemm128_kernel(
    const float* __restrict__ A, const float* __restrict__ B,
    const float* __restrict__ W1, const float* __restrict__ W2,
    const float* __restrict__ bias, const float* __restrict__ scale,
    float* __restrict__ C, int M)
{
    __shared__ float As[64 * 36];
    __shared__ float Ws[32 * 128];

    const int t = threadIdx.x;
    const int colg = t & 31;
    const int rowg = t >> 5;
    const int row0 = blockIdx.x * 64;

    float acc[8][4];
#pragma unroll
    for (int j = 0; j < 8; j++)
#pragma unroll
        for (int c = 0; c < 4; c++) acc[j][c] = 0.f;

    const int nphase = (MODE == 2) ? 2 : 1;
    for (int phase = 0; phase < nphase; phase++) {
        const float* Ap = (MODE == 2 && phase == 1) ? B : A;
        const float* Wp = (MODE == 2 && phase == 1) ? W2 : W1;
        for (int kc = 0; kc < 128; kc += 32) {
#pragma unroll
            for (int i = 0; i < 2; i++) {
                int f4 = t + i * 256;
                int r = f4 >> 3;
                int c4 = f4 & 7;
                int grow = row0 + r;
                float4 v = make_float4(0.f, 0.f, 0.f, 0.f);
                if (grow < M) {
                    v = *(const float4*)(Ap + (size_t)grow * 128 + kc + c4 * 4);
                    if (MODE == 0) {
                        float4 v2 = *(const float4*)(B + (size_t)grow * 128 + kc + c4 * 4);
                        v.x += v2.x; v.y += v2.y; v.z += v2.z; v.w += v2.w;
                    }
                    if (MODE == 2 && phase == 0) {
                        float sc = scale[grow];
                        v.x *= sc; v.y *= sc; v.z *= sc; v.w *= sc;
                    }
                }
                *(float4*)(As + r * 36 + c4 * 4) = v;
            }
#pragma unroll
            for (int i = 0; i < 4; i++) {
                int f4 = t + i * 256;
                int wr = f4 >> 5;
                int wc = f4 & 31;
                *(float4*)(Ws + wr * 128 + wc * 4) =
                    *(const float4*)(Wp + (size_t)(kc + wr) * 128 + wc * 4);
            }
            __syncthreads();
#pragma unroll
            for (int k = 0; k < 32; k++) {
                float4 w = *(const float4*)(Ws + k * 128 + colg * 4);
#pragma unroll
                for (int j = 0; j < 8; j++) {
                    float a = As[(rowg * 8 + j) * 36 + k];
                    acc[j][0] += a * w.x;
                    acc[j][1] += a * w.y;
                    acc[j][2] += a * w.z;
                    acc[j][3] += a * w.w;
                }
            }
            __syncthreads();
        }
    }

    float4 bs = *(const float4*)(bias + colg * 4);
#pragma unroll
    for (int j = 0; j < 8; j++) {
        int grow = row0 + rowg * 8 + j;
        if (grow >= M) continue;
        float4 o;
        o.x = acc[j][0] + bs.x;
        o.y = acc[j][1] + bs.y;
        o.z = acc[j][2] + bs.z;
        o.w = acc[j][3] + bs.w;
        if (MODE == 0) {
            o.x = fmaxf(o.x, 0.f); o.y = fmaxf(o.y, 0.f);
            o.z = fmaxf(o.z, 0.f); o.w = fmaxf(o.w, 0.f);
        }
        *(float4*)(C + (size_t)grow * 128 + colg * 4) = o;
    }
}

// ---------------------------------------------------------------------------
// BatchNorm
// ---------------------------------------------------------------------------
__global__ void bn_stats_kernel(const float* __restrict__ h, float* __restrict__ stats, int n) {
    int col = threadIdx.x & 127;
    int half = threadIdx.x >> 7;
    float s = 0.f, s2 = 0.f;
    for (int i = blockIdx.x * 2 + half; i < n; i += gridDim.x * 2) {
        float v = h[(size_t)i * 128 + col];
        s += v;
        s2 += v * v;
    }
    __shared__ float ls[256], ls2[256];
    ls[threadIdx.x] = s;
    ls2[threadIdx.x] = s2;
    __syncthreads();
    if (threadIdx.x < 128) {
        atomicAdd(&stats[col], ls[threadIdx.x] + ls[threadIdx.x + 128]);
        atomicAdd(&stats[128 + col], ls2[threadIdx.x] + ls2[threadIdx.x + 128]);
    }
}

__global__ void bn_apply_relu_kernel(float* __restrict__ h, const float* __restrict__ stats,
                                     const float* __restrict__ gamma,
                                     const float* __restrict__ beta, int n) {
    int gid = blockIdx.x * blockDim.x + threadIdx.x;
    int i = gid >> 5;
    int c4 = gid & 31;
    if (i >= n) return;
    int col = c4 * 4;
    float inv_n = 1.0f / (float)n;
    float4 v = *(float4*)(h + (size_t)i * 128 + col);
    float o[4] = {v.x, v.y, v.z, v.w};
#pragma unroll
    for (int cc = 0; cc < 4; cc++) {
        float mu = stats[col + cc] * inv_n;
        float var = stats[128 + col + cc] * inv_n - mu * mu;
        float rs = rsqrtf(var + BN_EPS);
        o[cc] = fmaxf(gamma[col + cc] * (o[cc] - mu) * rs + beta[col + cc], 0.f);
    }
    *(float4*)(h + (size_t)i * 128 + col) = make_float4(o[0], o[1], o[2], o[3]);
}

// ---------------------------------------------------------------------------
// global mean pool (batch is sorted -> segment reduction via binary search)
// ---------------------------------------------------------------------------
__global__ void gstart_kernel(const int* __restrict__ batch, int* __restrict__ gstart, int n) {
    int g = blockIdx.x * blockDim.x + threadIdx.x;
    if (g > N_GRAPHS) return;
    int lo = 0, hi = n;
    while (lo < hi) {
        int mid = (lo + hi) >> 1;
        if (batch[mid] < g) lo = mid + 1; else hi = mid;
    }
    gstart[g] = lo;   // first index with batch[i] >= g; gstart[N_GRAPHS] = n
}

__global__ __launch_bounds__(128) void pool_mean_kernel(const float* __restrict__ h,
                                                        const int* __restrict__ gstart,
                                                        float* __restrict__ out) {
    int g = blockIdx.x;
    int col = threadIdx.x;
    int beg = gstart[g];
    int end = gstart[g + 1];
    float s = 0.f;
    for (int i = beg; i < end; i++) s += h[(size_t)i * 128 + col];
    float cnt = fmaxf((float)(end - beg), 1.0f);
    out[(size_t)g * 128 + col] = s / cnt;
}

// ---------------------------------------------------------------------------
extern "C" void kernel_launch(void* const* d_in, const int* in_sizes, int n_in,
                              void* d_out, int out_size, void* d_ws, size_t ws_size,
                              hipStream_t stream) {
    const float* x    = (const float*)d_in[0];
    const int*   ei   = (const int*)d_in[1];
    const int*   src  = ei;
    const int*   dst  = ei + N_EDGES;
    const int*   batch = (const int*)d_in[2];
    const float* gw1  = (const float*)d_in[3];
    const float* gb1  = (const float*)d_in[4];
    const float* gw2  = (const float*)d_in[5];
    const float* gb2  = (const float*)d_in[6];
    const float* swl  = (const float*)d_in[7];
    const float* sbl  = (const float*)d_in[8];
    const float* swr  = (const float*)d_in[9];
    const float* bng  = (const float*)d_in[10];
    const float* bnb  = (const float*)d_in[11];
    float* out = (float*)d_out;

    // workspace layout (4B units)
    float* ws      = (float*)d_ws;
    float* hA      = ws;                     // 6.4M
    float* hB      = ws + 6400000;           // 6.4M
    float* agg     = ws + 12800000;          // 6.4M
    float* inv_deg = ws + 19200000;          // 50k
    float* stats   = ws + 19250000;          // 256
    int*   row_off = (int*)(ws + 19250256);  // 50001
    int*   cursor  = (int*)(ws + 19300257);  // 50000
    int*   csr_src = (int*)(ws + 19350257);  // 600000
    int*   gstart  = (int*)(ws + 19950257);  // 513

    const int elem_blocks = (N_NODES * 32 + 255) / 256;
    const int gemm_blocks = (N_NODES + 63) / 64;
    const int aggr_blocks = (N_NODES * 32 + 255) / 256;

    // ---- CSR build ----
    hipMemsetAsync(row_off, 0, (N_NODES + 1) * sizeof(int), stream);  // used as deg scratch? no: use cursor
    hipMemsetAsync(cursor, 0, N_NODES * sizeof(int), stream);
    deg_count_kernel<<<(N_EDGES + 255) / 256, 256, 0, stream>>>(dst, cursor, N_EDGES);
    scan_kernel<<<1, 1024, 0, stream>>>(cursor, row_off, N_NODES);
    copy_int_kernel<<<(N_NODES + 255) / 256, 256, 0, stream>>>(row_off, cursor, N_NODES);
    csr_fill_kernel<<<(N_EDGES + 255) / 256, 256, 0, stream>>>(src, dst, cursor, csr_src, N_EDGES);
    inv_deg_kernel<<<(N_NODES + 255) / 256, 256, 0, stream>>>(row_off, inv_deg, N_NODES);
    gstart_kernel<<<3, 256, 0, stream>>>(batch, gstart, N_NODES);

    // ---- GIN ----
    csr_aggregate_kernel<<<aggr_blocks, 256, 0, stream>>>(x, row_off, csr_src, agg, N_NODES);
    gemm128_kernel<0><<<gemm_blocks, 256, 0, stream>>>(x, agg, gw1, nullptr, gb1, nullptr, hA, N_NODES);
    gemm128_kernel<1><<<gemm_blocks, 256, 0, stream>>>(hA, nullptr, gw2, nullptr, gb2, nullptr, hB, N_NODES);
    hipMemsetAsync(stats, 0, 256 * sizeof(float), stream);
    bn_stats_kernel<<<256, 256, 0, stream>>>(hB, stats, N_NODES);
    bn_apply_relu_kernel<<<elem_blocks, 256, 0, stream>>>(hB, stats, bng + 0 * HID, bnb + 0 * HID, N_NODES);

    // ---- SAGE 0 ----
    csr_aggregate_kernel<<<aggr_blocks, 256, 0, stream>>>(hB, row_off, csr_src, agg, N_NODES);
    gemm128_kernel<2><<<gemm_blocks, 256, 0, stream>>>(agg, hB, swl + 0 * HID * HID, swr + 0 * HID * HID,
                                                       sbl + 0 * HID, inv_deg, hA, N_NODES);
    hipMemsetAsync(stats, 0, 256 * sizeof(float), stream);
    bn_stats_kernel<<<256, 256, 0, stream>>>(hA, stats, N_NODES);
    bn_apply_relu_kernel<<<elem_blocks, 256, 0, stream>>>(hA, stats, bng + 1 * HID, bnb + 1 * HID, N_NODES);

    // ---- SAGE 1 ----
    csr_aggregate_kernel<<<aggr_blocks, 256, 0, stream>>>(hA, row_off, csr_src, agg, N_NODES);
    gemm128_kernel<2><<<gemm_blocks, 256, 0, stream>>>(agg, hA, swl + 1 * HID * HID, swr + 1 * HID * HID,
                                                       sbl + 1 * HID, inv_deg, hB, N_NODES);
    hipMemsetAsync(stats, 0, 256 * sizeof(float), stream);
    bn_stats_kernel<<<256, 256, 0, stream>>>(hB, stats, N_NODES);
    bn_apply_relu_kernel<<<elem_blocks, 256, 0, stream>>>(hB, stats, bng + 2 * HID, bnb + 2 * HID, N_NODES);

    // ---- pool ----
    pool_mean_kernel<<<N_GRAPHS, 128, 0, stream>>>(hB, gstart, out);
}

// Round 3
// 537.182 us; speedup vs baseline: 6.7696x; 1.3447x over previous
//
#include <hip/hip_runtime.h>

#define N_NODES 50000
#define N_EDGES 600000
#define HID 128
#define N_GRAPHS 512
#define BN_EPS 1e-5f

// ---------------------------------------------------------------------------
// CSR build
// ---------------------------------------------------------------------------
__global__ void deg_count_kernel(const int* __restrict__ dst, int* __restrict__ deg, int nE) {
    int e = blockIdx.x * blockDim.x + threadIdx.x;
    if (e < nE) atomicAdd(&deg[dst[e]], 1);
}

// Per-block scan + atomic block-base allocation. Ranges are disjoint and
// contiguous per node; global ordering is irrelevant for correctness.
// Reads deg from cursor[], overwrites cursor[] and row_beg[] with range start.
__global__ __launch_bounds__(256) void alloc_kernel(int* __restrict__ cursor,
                                                    int* __restrict__ row_beg,
                                                    float* __restrict__ inv_deg,
                                                    int* __restrict__ total, int n) {
    __shared__ int tmp[256];
    __shared__ int base;
    int i = blockIdx.x * 256 + threadIdx.x;
    int d = (i < n) ? cursor[i] : 0;
    tmp[threadIdx.x] = d;
    __syncthreads();
#pragma unroll
    for (int off = 1; off < 256; off <<= 1) {
        int v = (threadIdx.x >= off) ? tmp[threadIdx.x - off] : 0;
        __syncthreads();
        tmp[threadIdx.x] += v;
        __syncthreads();
    }
    if (threadIdx.x == 255) base = atomicAdd(total, tmp[255]);
    __syncthreads();
    if (i < n) {
        int b = base + tmp[threadIdx.x] - d;   // exclusive within block + block base
        row_beg[i] = b;
        cursor[i] = b;
        inv_deg[i] = 1.0f / fmaxf((float)d, 1.0f);
    }
}

__global__ void csr_fill_kernel(const int* __restrict__ src, const int* __restrict__ dst,
                                int* __restrict__ cursor, int* __restrict__ csr_src, int nE) {
    int e = blockIdx.x * blockDim.x + threadIdx.x;
    if (e < nE) {
        int pos = atomicAdd(&cursor[dst[e]], 1);
        csr_src[pos] = src[e];
    }
}
// after csr_fill, cursor[i] == row_beg[i] + deg[i] == range end.

// ---------------------------------------------------------------------------
// gather aggregation; AFF: apply y = relu(v*cs[col]+sh[col]) to gathered rows
// ---------------------------------------------------------------------------
template<bool AFF>
__global__ void csr_aggregate_kernel(const float* __restrict__ feat,
                                     const int* __restrict__ row_beg,
                                     const int* __restrict__ row_end,
                                     const int* __restrict__ csr_src,
                                     const float* __restrict__ cs,
                                     const float* __restrict__ sh,
                                     float* __restrict__ agg, int n) {
    int gid = blockIdx.x * blockDim.x + threadIdx.x;
    int node = gid >> 5;
    int lane = gid & 31;
    if (node >= n) return;
    int beg = row_beg[node];
    int end = row_end[node];
    float4 cs4 = make_float4(0.f,0.f,0.f,0.f), sh4 = cs4;
    if (AFF) {
        cs4 = *(const float4*)(cs + lane * 4);
        sh4 = *(const float4*)(sh + lane * 4);
    }
    float4 acc = make_float4(0.f, 0.f, 0.f, 0.f);
    int e = beg;
    for (; e + 1 < end; e += 2) {
        int s0 = csr_src[e];
        int s1 = csr_src[e + 1];
        float4 v0 = ((const float4*)(feat + (size_t)s0 * HID))[lane];
        float4 v1 = ((const float4*)(feat + (size_t)s1 * HID))[lane];
        if (AFF) {
            v0.x = fmaxf(v0.x * cs4.x + sh4.x, 0.f); v1.x = fmaxf(v1.x * cs4.x + sh4.x, 0.f);
            v0.y = fmaxf(v0.y * cs4.y + sh4.y, 0.f); v1.y = fmaxf(v1.y * cs4.y + sh4.y, 0.f);
            v0.z = fmaxf(v0.z * cs4.z + sh4.z, 0.f); v1.z = fmaxf(v1.z * cs4.z + sh4.z, 0.f);
            v0.w = fmaxf(v0.w * cs4.w + sh4.w, 0.f); v1.w = fmaxf(v1.w * cs4.w + sh4.w, 0.f);
        }
        acc.x += v0.x + v1.x;
        acc.y += v0.y + v1.y;
        acc.z += v0.z + v1.z;
        acc.w += v0.w + v1.w;
    }
    if (e < end) {
        int s0 = csr_src[e];
        float4 v0 = ((const float4*)(feat + (size_t)s0 * HID))[lane];
        if (AFF) {
            v0.x = fmaxf(v0.x * cs4.x + sh4.x, 0.f);
            v0.y = fmaxf(v0.y * cs4.y + sh4.y, 0.f);
            v0.z = fmaxf(v0.z * cs4.z + sh4.z, 0.f);
            v0.w = fmaxf(v0.w * cs4.w + sh4.w, 0.f);
        }
        acc.x += v0.x; acc.y += v0.y; acc.z += v0.z; acc.w += v0.w;
    }
    ((float4*)(agg + (size_t)node * HID))[lane] = acc;
}

// ---------------------------------------------------------------------------
// GEMM, N = K = 128 (MODE 2: two phases, K = 256).
// MODE 0: C = relu((A + B) @ W1 + bias)
// MODE 1: C = A @ W1 + bias
// MODE 2: C = (A*scale[i]) @ W1 + act(B) @ W2 + bias,
//         act(v) = AFFB ? relu(v*csB+shB) : v
// STATS: atomically accumulate column sum/sumsq of C into stats[0:128]/[128:256]
// ---------------------------------------------------------------------------
template<int MODE, bool STATS, bool AFFB>
__global__ __launch_bounds__(256) void gemm128_kernel(
    const float* __restrict__ A, const float* __restrict__ B,
    const float* __restrict__ W1, const float* __restrict__ W2,
    const float* __restrict__ bias, const float* __restrict__ scale,
    const float* __restrict__ csB, const float* __restrict__ shB,
    float* __restrict__ stats, float* __restrict__ C, int M)
{
    __shared__ float As[64 * 36];
    __shared__ float Ws[32 * 128];

    const int t = threadIdx.x;
    const int colg = t & 31;
    const int rowg = t >> 5;
    const int row0 = blockIdx.x * 64;

    float acc[8][4];
#pragma unroll
    for (int j = 0; j < 8; j++)
#pragma unroll
        for (int c = 0; c < 4; c++) acc[j][c] = 0.f;

    const int nphase = (MODE == 2) ? 2 : 1;
    for (int phase = 0; phase < nphase; phase++) {
        const float* Ap = (MODE == 2 && phase == 1) ? B : A;
        const float* Wp = (MODE == 2 && phase == 1) ? W2 : W1;
        for (int kc = 0; kc < 128; kc += 32) {
#pragma unroll
            for (int i = 0; i < 2; i++) {
                int f4 = t + i * 256;
                int r = f4 >> 3;
                int c4 = f4 & 7;
                int grow = row0 + r;
                float4 v = make_float4(0.f, 0.f, 0.f, 0.f);
                if (grow < M) {
                    v = *(const float4*)(Ap + (size_t)grow * 128 + kc + c4 * 4);
                    if (MODE == 0) {
                        float4 v2 = *(const float4*)(B + (size_t)grow * 128 + kc + c4 * 4);
                        v.x += v2.x; v.y += v2.y; v.z += v2.z; v.w += v2.w;
                    }
                    if (MODE == 2 && phase == 0) {
                        float sc = scale[grow];
                        v.x *= sc; v.y *= sc; v.z *= sc; v.w *= sc;
                    }
                    if (MODE == 2 && phase == 1 && AFFB) {
                        float4 cs4 = *(const float4*)(csB + kc + c4 * 4);
                        float4 sh4 = *(const float4*)(shB + kc + c4 * 4);
                        v.x = fmaxf(v.x * cs4.x + sh4.x, 0.f);
                        v.y = fmaxf(v.y * cs4.y + sh4.y, 0.f);
                        v.z = fmaxf(v.z * cs4.z + sh4.z, 0.f);
                        v.w = fmaxf(v.w * cs4.w + sh4.w, 0.f);
                    }
                }
                *(float4*)(As + r * 36 + c4 * 4) = v;
            }
#pragma unroll
            for (int i = 0; i < 4; i++) {
                int f4 = t + i * 256;
                int wr = f4 >> 5;
                int wc = f4 & 31;
                *(float4*)(Ws + wr * 128 + wc * 4) =
                    *(const float4*)(Wp + (size_t)(kc + wr) * 128 + wc * 4);
            }
            __syncthreads();
#pragma unroll
            for (int k = 0; k < 32; k++) {
                float4 w = *(const float4*)(Ws + k * 128 + colg * 4);
#pragma unroll
                for (int j = 0; j < 8; j++) {
                    float a = As[(rowg * 8 + j) * 36 + k];
                    acc[j][0] += a * w.x;
                    acc[j][1] += a * w.y;
                    acc[j][2] += a * w.z;
                    acc[j][3] += a * w.w;
                }
            }
            __syncthreads();
        }
    }

    float4 bs = *(const float4*)(bias + colg * 4);
    float psum[4] = {0.f, 0.f, 0.f, 0.f};
    float psq[4]  = {0.f, 0.f, 0.f, 0.f};
#pragma unroll
    for (int j = 0; j < 8; j++) {
        int grow = row0 + rowg * 8 + j;
        if (grow >= M) continue;
        float o[4];
        o[0] = acc[j][0] + bs.x;
        o[1] = acc[j][1] + bs.y;
        o[2] = acc[j][2] + bs.z;
        o[3] = acc[j][3] + bs.w;
        if (MODE == 0) {
#pragma unroll
            for (int c = 0; c < 4; c++) o[c] = fmaxf(o[c], 0.f);
        }
        if (STATS) {
#pragma unroll
            for (int c = 0; c < 4; c++) { psum[c] += o[c]; psq[c] += o[c] * o[c]; }
        }
        *(float4*)(C + (size_t)grow * 128 + colg * 4) = make_float4(o[0], o[1], o[2], o[3]);
    }

    if (STATS) {
        float* red = As;  // reuse: 8 x 128 = 1024 floats needed, As has 2304
#pragma unroll
        for (int c = 0; c < 4; c++) red[rowg * 128 + colg * 4 + c] = psum[c];
        __syncthreads();
        if (t < 128) {
            float s = 0.f;
#pragma unroll
            for (int r = 0; r < 8; r++) s += red[r * 128 + t];
            atomicAdd(&stats[t], s);
        }
        __syncthreads();
#pragma unroll
        for (int c = 0; c < 4; c++) red[rowg * 128 + colg * 4 + c] = psq[c];
        __syncthreads();
        if (t < 128) {
            float s = 0.f;
#pragma unroll
            for (int r = 0; r < 8; r++) s += red[r * 128 + t];
            atomicAdd(&stats[128 + t], s);
        }
    }
}

// ---------------------------------------------------------------------------
// BN finalize: stats -> per-column affine (cs, sh);  relu applied by consumers
// ---------------------------------------------------------------------------
__global__ void bn_finalize_kernel(const float* __restrict__ stats,
                                   const float* __restrict__ gamma,
                                   const float* __restrict__ beta,
                                   float* __restrict__ cs, float* __restrict__ sh) {
    int t = threadIdx.x;
    if (t >= 128) return;
    float inv_n = 1.0f / (float)N_NODES;
    float mu = stats[t] * inv_n;
    float var = stats[128 + t] * inv_n - mu * mu;
    float rs = rsqrtf(var + BN_EPS);
    float c = gamma[t] * rs;
    cs[t] = c;
    sh[t] = beta[t] - mu * c;
}

// ---------------------------------------------------------------------------
// global mean pool over sorted batch ids, with fused BN affine + relu
// ---------------------------------------------------------------------------
__global__ void gstart_kernel(const int* __restrict__ batch, int* __restrict__ gstart, int n) {
    int g = blockIdx.x * blockDim.x + threadIdx.x;
    if (g > N_GRAPHS) return;
    int lo = 0, hi = n;
    while (lo < hi) {
        int mid = (lo + hi) >> 1;
        if (batch[mid] < g) lo = mid + 1; else hi = mid;
    }
    gstart[g] = lo;
}

__global__ __launch_bounds__(128) void pool_mean_kernel(const float* __restrict__ h,
                                                        const int* __restrict__ gstart,
                                                        const float* __restrict__ cs,
                                                        const float* __restrict__ sh,
                                                        float* __restrict__ out) {
    int g = blockIdx.x;
    int col = threadIdx.x;
    int beg = gstart[g];
    int end = gstart[g + 1];
    float c = cs[col], b = sh[col];
    float s = 0.f;
    for (int i = beg; i < end; i++)
        s += fmaxf(h[(size_t)i * 128 + col] * c + b, 0.f);
    float cnt = fmaxf((float)(end - beg), 1.0f);
    out[(size_t)g * 128 + col] = s / cnt;
}

// ---------------------------------------------------------------------------
extern "C" void kernel_launch(void* const* d_in, const int* in_sizes, int n_in,
                              void* d_out, int out_size, void* d_ws, size_t ws_size,
                              hipStream_t stream) {
    const float* x    = (const float*)d_in[0];
    const int*   ei   = (const int*)d_in[1];
    const int*   src  = ei;
    const int*   dst  = ei + N_EDGES;
    const int*   batch = (const int*)d_in[2];
    const float* gw1  = (const float*)d_in[3];
    const float* gb1  = (const float*)d_in[4];
    const float* gw2  = (const float*)d_in[5];
    const float* gb2  = (const float*)d_in[6];
    const float* swl  = (const float*)d_in[7];
    const float* sbl  = (const float*)d_in[8];
    const float* swr  = (const float*)d_in[9];
    const float* bng  = (const float*)d_in[10];
    const float* bnb  = (const float*)d_in[11];
    float* out = (float*)d_out;

    // workspace layout (float units)
    float* ws      = (float*)d_ws;
    float* hA      = ws;                      // 6.4M
    float* hB      = ws + 6400000;            // 6.4M
    float* agg     = ws + 12800000;           // 6.4M
    float* inv_deg = ws + 19200000;           // 50000
    float* stats   = ws + 19250000;           // 3 x 256
    float* cs      = ws + 19250768;           // 3 x 128
    float* sh      = ws + 19251152;           // 3 x 128
    int*   row_beg = (int*)(ws + 19251536);   // 50000
    int*   cursor  = (int*)(ws + 19301536);   // 50000
    int*   csr_src = (int*)(ws + 19351536);   // 600000
    int*   gstart  = (int*)(ws + 19951536);   // 513
    int*   total   = (int*)(ws + 19952049);   // 1

    const int gemm_blocks = (N_NODES + 63) / 64;
    const int aggr_blocks = (N_NODES * 32 + 255) / 256;

    // ---- CSR build (no serial scan) ----
    hipMemsetAsync(cursor, 0, N_NODES * sizeof(int), stream);
    hipMemsetAsync(total, 0, sizeof(int), stream);
    hipMemsetAsync(stats, 0, 3 * 256 * sizeof(float), stream);
    deg_count_kernel<<<(N_EDGES + 255) / 256, 256, 0, stream>>>(dst, cursor, N_EDGES);
    alloc_kernel<<<(N_NODES + 255) / 256, 256, 0, stream>>>(cursor, row_beg, inv_deg, total, N_NODES);
    csr_fill_kernel<<<(N_EDGES + 255) / 256, 256, 0, stream>>>(src, dst, cursor, csr_src, N_EDGES);
    // cursor now holds range ends
    gstart_kernel<<<3, 256, 0, stream>>>(batch, gstart, N_NODES);

    // ---- GIN ----
    csr_aggregate_kernel<false><<<aggr_blocks, 256, 0, stream>>>(
        x, row_beg, cursor, csr_src, nullptr, nullptr, agg, N_NODES);
    gemm128_kernel<0, false, false><<<gemm_blocks, 256, 0, stream>>>(
        x, agg, gw1, nullptr, gb1, nullptr, nullptr, nullptr, nullptr, hA, N_NODES);
    gemm128_kernel<1, true, false><<<gemm_blocks, 256, 0, stream>>>(
        hA, nullptr, gw2, nullptr, gb2, nullptr, nullptr, nullptr, stats + 0, hB, N_NODES);
    bn_finalize_kernel<<<1, 128, 0, stream>>>(stats + 0, bng + 0 * HID, bnb + 0 * HID, cs + 0, sh + 0);

    // ---- SAGE 0 : h0pre = hB, act via cs0/sh0 ----
    csr_aggregate_kernel<true><<<aggr_blocks, 256, 0, stream>>>(
        hB, row_beg, cursor, csr_src, cs + 0, sh + 0, agg, N_NODES);
    gemm128_kernel<2, true, true><<<gemm_blocks, 256, 0, stream>>>(
        agg, hB, swl + 0 * HID * HID, swr + 0 * HID * HID, sbl + 0 * HID, inv_deg,
        cs + 0, sh + 0, stats + 256, hA, N_NODES);
    bn_finalize_kernel<<<1, 128, 0, stream>>>(stats + 256, bng + 1 * HID, bnb + 1 * HID, cs + 128, sh + 128);

    // ---- SAGE 1 : h1pre = hA, act via cs1/sh1 ----
    csr_aggregate_kernel<true><<<aggr_blocks, 256, 0, stream>>>(
        hA, row_beg, cursor, csr_src, cs + 128, sh + 128, agg, N_NODES);
    gemm128_kernel<2, true, true><<<gemm_blocks, 256, 0, stream>>>(
        agg, hA, swl + 1 * HID * HID, swr + 1 * HID * HID, sbl + 1 * HID, inv_deg,
        cs + 128, sh + 128, stats + 512, hB, N_NODES);
    bn_finalize_kernel<<<1, 128, 0, stream>>>(stats + 512, bng + 2 * HID, bnb + 2 * HID, cs + 256, sh + 256);

    // ---- pool (h2pre = hB, act via cs2/sh2) ----
    pool_mean_kernel<<<N_GRAPHS, 128, 0, stream>>>(hB, gstart, cs + 256, sh + 256, out);
}

// Round 4
// 515.345 us; speedup vs baseline: 7.0565x; 1.0424x over previous
//
#include <hip/hip_runtime.h>

#define N_NODES 50000
#define N_EDGES 600000
#define HID 128
#define N_GRAPHS 512
#define BN_EPS 1e-5f

// ---------------------------------------------------------------------------
// CSR build
// ---------------------------------------------------------------------------
__global__ void deg_count_kernel(const int* __restrict__ dst, int* __restrict__ deg, int nE) {
    int e = blockIdx.x * blockDim.x + threadIdx.x;
    if (e < nE) atomicAdd(&deg[dst[e]], 1);
}

__global__ __launch_bounds__(256) void alloc_kernel(int* __restrict__ cursor,
                                                    int* __restrict__ row_beg,
                                                    float* __restrict__ inv_deg,
                                                    int* __restrict__ total, int n) {
    __shared__ int tmp[256];
    __shared__ int base;
    int i = blockIdx.x * 256 + threadIdx.x;
    int d = (i < n) ? cursor[i] : 0;
    tmp[threadIdx.x] = d;
    __syncthreads();
#pragma unroll
    for (int off = 1; off < 256; off <<= 1) {
        int v = (threadIdx.x >= off) ? tmp[threadIdx.x - off] : 0;
        __syncthreads();
        tmp[threadIdx.x] += v;
        __syncthreads();
    }
    if (threadIdx.x == 255) base = atomicAdd(total, tmp[255]);
    __syncthreads();
    if (i < n) {
        int b = base + tmp[threadIdx.x] - d;
        row_beg[i] = b;
        cursor[i] = b;
        inv_deg[i] = 1.0f / fmaxf((float)d, 1.0f);
    }
}

__global__ void csr_fill_kernel(const int* __restrict__ src, const int* __restrict__ dst,
                                int* __restrict__ cursor, int* __restrict__ csr_src, int nE) {
    int e = blockIdx.x * blockDim.x + threadIdx.x;
    if (e < nE) {
        int pos = atomicAdd(&cursor[dst[e]], 1);
        csr_src[pos] = src[e];
    }
}

// ---------------------------------------------------------------------------
// gather aggregation; AFF: apply y = relu(v*cs[col]+sh[col]) to gathered rows
// ---------------------------------------------------------------------------
template<bool AFF>
__global__ void csr_aggregate_kernel(const float* __restrict__ feat,
                                     const int* __restrict__ row_beg,
                                     const int* __restrict__ row_end,
                                     const int* __restrict__ csr_src,
                                     const float* __restrict__ cs,
                                     const float* __restrict__ sh,
                                     float* __restrict__ agg, int n) {
    int gid = blockIdx.x * blockDim.x + threadIdx.x;
    int node = gid >> 5;
    int lane = gid & 31;
    if (node >= n) return;
    int beg = row_beg[node];
    int end = row_end[node];
    float4 cs4 = make_float4(0.f,0.f,0.f,0.f), sh4 = cs4;
    if (AFF) {
        cs4 = *(const float4*)(cs + lane * 4);
        sh4 = *(const float4*)(sh + lane * 4);
    }
    float4 acc = make_float4(0.f, 0.f, 0.f, 0.f);
    int e = beg;
    for (; e + 1 < end; e += 2) {
        int s0 = csr_src[e];
        int s1 = csr_src[e + 1];
        float4 v0 = ((const float4*)(feat + (size_t)s0 * HID))[lane];
        float4 v1 = ((const float4*)(feat + (size_t)s1 * HID))[lane];
        if (AFF) {
            v0.x = fmaxf(v0.x * cs4.x + sh4.x, 0.f); v1.x = fmaxf(v1.x * cs4.x + sh4.x, 0.f);
            v0.y = fmaxf(v0.y * cs4.y + sh4.y, 0.f); v1.y = fmaxf(v1.y * cs4.y + sh4.y, 0.f);
            v0.z = fmaxf(v0.z * cs4.z + sh4.z, 0.f); v1.z = fmaxf(v1.z * cs4.z + sh4.z, 0.f);
            v0.w = fmaxf(v0.w * cs4.w + sh4.w, 0.f); v1.w = fmaxf(v1.w * cs4.w + sh4.w, 0.f);
        }
        acc.x += v0.x + v1.x;
        acc.y += v0.y + v1.y;
        acc.z += v0.z + v1.z;
        acc.w += v0.w + v1.w;
    }
    if (e < end) {
        int s0 = csr_src[e];
        float4 v0 = ((const float4*)(feat + (size_t)s0 * HID))[lane];
        if (AFF) {
            v0.x = fmaxf(v0.x * cs4.x + sh4.x, 0.f);
            v0.y = fmaxf(v0.y * cs4.y + sh4.y, 0.f);
            v0.z = fmaxf(v0.z * cs4.z + sh4.z, 0.f);
            v0.w = fmaxf(v0.w * cs4.w + sh4.w, 0.f);
        }
        acc.x += v0.x; acc.y += v0.y; acc.z += v0.z; acc.w += v0.w;
    }
    ((float4*)(agg + (size_t)node * HID))[lane] = acc;
}

// ---------------------------------------------------------------------------
// 128x128-tile GEMM, 256 threads, 8x8 per-thread register blocking.
// As: [128 rows][32 k] pad 33 (a-read: 4 rowg addrs, banks {0,8,16,24} - free)
// Ws: [32 k][128 cols]
//
// MODE 0 (fused GIN):  T1 = relu((A1+A2) @ W1 + b1);  C = T1 @ W2 + b2
// MODE 2 (SAGE):       C = (A1*scale) @ W1 + act(A2) @ W2 + b1
//                      act(v) = AFFB ? relu(v*csB+shB) : v
// STATS: accumulate column sum/sumsq of C into stats[0:128]/[128:256]
// ---------------------------------------------------------------------------
template<int MODE, bool STATS, bool AFFB>
__global__ __launch_bounds__(256, 2) void gemm_tile_kernel(
    const float* __restrict__ A1, const float* __restrict__ A2,
    const float* __restrict__ W1, const float* __restrict__ W2,
    const float* __restrict__ b1, const float* __restrict__ b2,
    const float* __restrict__ scale,
    const float* __restrict__ csB, const float* __restrict__ shB,
    float* __restrict__ stats, float* __restrict__ C, int M)
{
    __shared__ float As[128 * 33];
    __shared__ float Ws[32 * 128];

    const int t = threadIdx.x;
    const int colg = t & 15;   const int col0  = colg * 8;
    const int rowg = t >> 4;   const int row0r = rowg * 8;
    const int row0 = blockIdx.x * 128;

    float acc[8][8];
#pragma unroll
    for (int j = 0; j < 8; j++)
#pragma unroll
        for (int c = 0; c < 8; c++) acc[j][c] = 0.f;

    // =================== phase 1: A-from-global @ W1 ===================
    for (int kc = 0; kc < 128; kc += 32) {
        // stage A: 1024 float4, 4 per thread
#pragma unroll
        for (int i = 0; i < 4; i++) {
            int f4 = t + i * 256;
            int r = f4 >> 3;
            int c4 = f4 & 7;
            int grow = row0 + r;
            float4 v = make_float4(0.f, 0.f, 0.f, 0.f);
            if (grow < M) {
                v = *(const float4*)(A1 + (size_t)grow * 128 + kc + c4 * 4);
                if (MODE == 0) {
                    float4 v2 = *(const float4*)(A2 + (size_t)grow * 128 + kc + c4 * 4);
                    v.x += v2.x; v.y += v2.y; v.z += v2.z; v.w += v2.w;
                } else {
                    float sc = scale[grow];
                    v.x *= sc; v.y *= sc; v.z *= sc; v.w *= sc;
                }
            }
            float* p = As + r * 33 + c4 * 4;
            p[0] = v.x; p[1] = v.y; p[2] = v.z; p[3] = v.w;
        }
        // stage W1 chunk
#pragma unroll
        for (int i = 0; i < 4; i++) {
            int f4 = t + i * 256;
            int wr = f4 >> 5;
            int wc = f4 & 31;
            ((float4*)Ws)[wr * 32 + wc] = ((const float4*)(W1 + (size_t)(kc + wr) * 128))[wc];
        }
        __syncthreads();
#pragma unroll 2
        for (int k = 0; k < 32; k++) {
            float4 bb0 = *(const float4*)(Ws + k * 128 + col0);
            float4 bb1 = *(const float4*)(Ws + k * 128 + col0 + 4);
            float bv[8] = {bb0.x, bb0.y, bb0.z, bb0.w, bb1.x, bb1.y, bb1.z, bb1.w};
#pragma unroll
            for (int j = 0; j < 8; j++) {
                float a = As[(row0r + j) * 33 + k];
#pragma unroll
                for (int c = 0; c < 8; c++) acc[j][c] += a * bv[c];
            }
        }
        __syncthreads();
    }

    float out[8][8];

    if (MODE == 0) {
        // T1 = relu(acc + b1), kept in acc
        float4 bs0 = *(const float4*)(b1 + col0);
        float4 bs1 = *(const float4*)(b1 + col0 + 4);
        float bv[8] = {bs0.x, bs0.y, bs0.z, bs0.w, bs1.x, bs1.y, bs1.z, bs1.w};
#pragma unroll
        for (int j = 0; j < 8; j++)
#pragma unroll
            for (int c = 0; c < 8; c++) acc[j][c] = fmaxf(acc[j][c] + bv[c], 0.f);

        // =================== phase 2: T1 @ W2 (As chunks from registers) ===
        float acc2[8][8];
#pragma unroll
        for (int j = 0; j < 8; j++)
#pragma unroll
            for (int c = 0; c < 8; c++) acc2[j][c] = 0.f;

        for (int p = 0; p < 4; p++) {
            if ((colg >> 2) == p) {
                int lc = (colg & 3) * 8;
#pragma unroll
                for (int j = 0; j < 8; j++) {
                    float* q = As + (row0r + j) * 33 + lc;
#pragma unroll
                    for (int c = 0; c < 8; c++) q[c] = acc[j][c];
                }
            }
#pragma unroll
            for (int i = 0; i < 4; i++) {
                int f4 = t + i * 256;
                int wr = f4 >> 5;
                int wc = f4 & 31;
                ((float4*)Ws)[wr * 32 + wc] = ((const float4*)(W2 + (size_t)(p * 32 + wr) * 128))[wc];
            }
            __syncthreads();
#pragma unroll 2
            for (int k = 0; k < 32; k++) {
                float4 bb0 = *(const float4*)(Ws + k * 128 + col0);
                float4 bb1 = *(const float4*)(Ws + k * 128 + col0 + 4);
                float bv[8] = {bb0.x, bb0.y, bb0.z, bb0.w, bb1.x, bb1.y, bb1.z, bb1.w};
#pragma unroll
                for (int j = 0; j < 8; j++) {
                    float a = As[(row0r + j) * 33 + k];
#pragma unroll
                    for (int c = 0; c < 8; c++) acc2[j][c] += a * bv[c];
                }
            }
            __syncthreads();
        }
        float4 c0 = *(const float4*)(b2 + col0);
        float4 c1 = *(const float4*)(b2 + col0 + 4);
        float bv2[8] = {c0.x, c0.y, c0.z, c0.w, c1.x, c1.y, c1.z, c1.w};
#pragma unroll
        for (int j = 0; j < 8; j++)
#pragma unroll
            for (int c = 0; c < 8; c++) out[j][c] = acc2[j][c] + bv2[c];
    } else {
        // =================== phase 2: act(A2) @ W2 ===================
        for (int kc = 0; kc < 128; kc += 32) {
#pragma unroll
            for (int i = 0; i < 4; i++) {
                int f4 = t + i * 256;
                int r = f4 >> 3;
                int c4 = f4 & 7;
                int grow = row0 + r;
                float4 v = make_float4(0.f, 0.f, 0.f, 0.f);
                if (grow < M) {
                    v = *(const float4*)(A2 + (size_t)grow * 128 + kc + c4 * 4);
                    if (AFFB) {
                        float4 cs4 = *(const float4*)(csB + kc + c4 * 4);
                        float4 sh4 = *(const float4*)(shB + kc + c4 * 4);
                        v.x = fmaxf(v.x * cs4.x + sh4.x, 0.f);
                        v.y = fmaxf(v.y * cs4.y + sh4.y, 0.f);
                        v.z = fmaxf(v.z * cs4.z + sh4.z, 0.f);
                        v.w = fmaxf(v.w * cs4.w + sh4.w, 0.f);
                    }
                }
                float* p = As + r * 33 + c4 * 4;
                p[0] = v.x; p[1] = v.y; p[2] = v.z; p[3] = v.w;
            }
#pragma unroll
            for (int i = 0; i < 4; i++) {
                int f4 = t + i * 256;
                int wr = f4 >> 5;
                int wc = f4 & 31;
                ((float4*)Ws)[wr * 32 + wc] = ((const float4*)(W2 + (size_t)(kc + wr) * 128))[wc];
            }
            __syncthreads();
#pragma unroll 2
            for (int k = 0; k < 32; k++) {
                float4 bb0 = *(const float4*)(Ws + k * 128 + col0);
                float4 bb1 = *(const float4*)(Ws + k * 128 + col0 + 4);
                float bv[8] = {bb0.x, bb0.y, bb0.z, bb0.w, bb1.x, bb1.y, bb1.z, bb1.w};
#pragma unroll
                for (int j = 0; j < 8; j++) {
                    float a = As[(row0r + j) * 33 + k];
#pragma unroll
                    for (int c = 0; c < 8; c++) acc[j][c] += a * bv[c];
                }
            }
            __syncthreads();
        }
        float4 c0 = *(const float4*)(b1 + col0);
        float4 c1 = *(const float4*)(b1 + col0 + 4);
        float bv2[8] = {c0.x, c0.y, c0.z, c0.w, c1.x, c1.y, c1.z, c1.w};
#pragma unroll
        for (int j = 0; j < 8; j++)
#pragma unroll
            for (int c = 0; c < 8; c++) out[j][c] = acc[j][c] + bv2[c];
    }

    // =================== store + stats ===================
    float psum[8] = {0,0,0,0,0,0,0,0};
    float psq[8]  = {0,0,0,0,0,0,0,0};
#pragma unroll
    for (int j = 0; j < 8; j++) {
        int grow = row0 + row0r + j;
        if (grow >= M) continue;
        if (STATS) {
#pragma unroll
            for (int c = 0; c < 8; c++) { psum[c] += out[j][c]; psq[c] += out[j][c] * out[j][c]; }
        }
        *(float4*)(C + (size_t)grow * 128 + col0)     = make_float4(out[j][0], out[j][1], out[j][2], out[j][3]);
        *(float4*)(C + (size_t)grow * 128 + col0 + 4) = make_float4(out[j][4], out[j][5], out[j][6], out[j][7]);
    }

    if (STATS) {
        float* red = As;  // 16 x 128 = 2048 floats
#pragma unroll
        for (int c = 0; c < 8; c++) red[rowg * 128 + col0 + c] = psum[c];
        __syncthreads();
        if (t < 128) {
            float s = 0.f;
#pragma unroll
            for (int r = 0; r < 16; r++) s += red[r * 128 + t];
            atomicAdd(&stats[t], s);
        }
        __syncthreads();
#pragma unroll
        for (int c = 0; c < 8; c++) red[rowg * 128 + col0 + c] = psq[c];
        __syncthreads();
        if (t < 128) {
            float s = 0.f;
#pragma unroll
            for (int r = 0; r < 16; r++) s += red[r * 128 + t];
            atomicAdd(&stats[128 + t], s);
        }
    }
}

// ---------------------------------------------------------------------------
// BN finalize
// ---------------------------------------------------------------------------
__global__ void bn_finalize_kernel(const float* __restrict__ stats,
                                   const float* __restrict__ gamma,
                                   const float* __restrict__ beta,
                                   float* __restrict__ cs, float* __restrict__ sh) {
    int t = threadIdx.x;
    if (t >= 128) return;
    float inv_n = 1.0f / (float)N_NODES;
    float mu = stats[t] * inv_n;
    float var = stats[128 + t] * inv_n - mu * mu;
    float rs = rsqrtf(var + BN_EPS);
    float c = gamma[t] * rs;
    cs[t] = c;
    sh[t] = beta[t] - mu * c;
}

// ---------------------------------------------------------------------------
// global mean pool (fused BN affine + relu)
// ---------------------------------------------------------------------------
__global__ void gstart_kernel(const int* __restrict__ batch, int* __restrict__ gstart, int n) {
    int g = blockIdx.x * blockDim.x + threadIdx.x;
    if (g > N_GRAPHS) return;
    int lo = 0, hi = n;
    while (lo < hi) {
        int mid = (lo + hi) >> 1;
        if (batch[mid] < g) lo = mid + 1; else hi = mid;
    }
    gstart[g] = lo;
}

__global__ __launch_bounds__(128) void pool_mean_kernel(const float* __restrict__ h,
                                                        const int* __restrict__ gstart,
                                                        const float* __restrict__ cs,
                                                        const float* __restrict__ sh,
                                                        float* __restrict__ out) {
    int g = blockIdx.x;
    int col = threadIdx.x;
    int beg = gstart[g];
    int end = gstart[g + 1];
    float c = cs[col], b = sh[col];
    float s = 0.f;
    for (int i = beg; i < end; i++)
        s += fmaxf(h[(size_t)i * 128 + col] * c + b, 0.f);
    float cnt = fmaxf((float)(end - beg), 1.0f);
    out[(size_t)g * 128 + col] = s / cnt;
}

// ---------------------------------------------------------------------------
extern "C" void kernel_launch(void* const* d_in, const int* in_sizes, int n_in,
                              void* d_out, int out_size, void* d_ws, size_t ws_size,
                              hipStream_t stream) {
    const float* x    = (const float*)d_in[0];
    const int*   ei   = (const int*)d_in[1];
    const int*   src  = ei;
    const int*   dst  = ei + N_EDGES;
    const int*   batch = (const int*)d_in[2];
    const float* gw1  = (const float*)d_in[3];
    const float* gb1  = (const float*)d_in[4];
    const float* gw2  = (const float*)d_in[5];
    const float* gb2  = (const float*)d_in[6];
    const float* swl  = (const float*)d_in[7];
    const float* sbl  = (const float*)d_in[8];
    const float* swr  = (const float*)d_in[9];
    const float* bng  = (const float*)d_in[10];
    const float* bnb  = (const float*)d_in[11];
    float* out = (float*)d_out;

    float* ws      = (float*)d_ws;
    float* hA      = ws;                      // 6.4M
    float* hB      = ws + 6400000;            // 6.4M
    float* agg     = ws + 12800000;           // 6.4M
    float* inv_deg = ws + 19200000;           // 50000
    float* stats   = ws + 19250000;           // 3 x 256
    float* cs      = ws + 19250768;           // 3 x 128
    float* sh      = ws + 19251152;           // 3 x 128
    int*   row_beg = (int*)(ws + 19251536);   // 50000
    int*   cursor  = (int*)(ws + 19301536);   // 50000
    int*   csr_src = (int*)(ws + 19351536);   // 600000
    int*   gstart  = (int*)(ws + 19951536);   // 513
    int*   total   = (int*)(ws + 19952049);   // 1

    const int gemm_blocks = (N_NODES + 127) / 128;
    const int aggr_blocks = (N_NODES * 32 + 255) / 256;

    // ---- CSR build ----
    hipMemsetAsync(cursor, 0, N_NODES * sizeof(int), stream);
    hipMemsetAsync(total, 0, sizeof(int), stream);
    hipMemsetAsync(stats, 0, 3 * 256 * sizeof(float), stream);
    deg_count_kernel<<<(N_EDGES + 255) / 256, 256, 0, stream>>>(dst, cursor, N_EDGES);
    alloc_kernel<<<(N_NODES + 255) / 256, 256, 0, stream>>>(cursor, row_beg, inv_deg, total, N_NODES);
    csr_fill_kernel<<<(N_EDGES + 255) / 256, 256, 0, stream>>>(src, dst, cursor, csr_src, N_EDGES);
    gstart_kernel<<<3, 256, 0, stream>>>(batch, gstart, N_NODES);

    // ---- GIN (fused two GEMMs) ----
    csr_aggregate_kernel<false><<<aggr_blocks, 256, 0, stream>>>(
        x, row_beg, cursor, csr_src, nullptr, nullptr, agg, N_NODES);
    gemm_tile_kernel<0, true, false><<<gemm_blocks, 256, 0, stream>>>(
        x, agg, gw1, gw2, gb1, gb2, nullptr, nullptr, nullptr, stats + 0, hB, N_NODES);
    bn_finalize_kernel<<<1, 128, 0, stream>>>(stats + 0, bng + 0 * HID, bnb + 0 * HID, cs + 0, sh + 0);

    // ---- SAGE 0 ----
    csr_aggregate_kernel<true><<<aggr_blocks, 256, 0, stream>>>(
        hB, row_beg, cursor, csr_src, cs + 0, sh + 0, agg, N_NODES);
    gemm_tile_kernel<2, true, true><<<gemm_blocks, 256, 0, stream>>>(
        agg, hB, swl + 0 * HID * HID, swr + 0 * HID * HID, sbl + 0 * HID, nullptr,
        inv_deg, cs + 0, sh + 0, stats + 256, hA, N_NODES);
    bn_finalize_kernel<<<1, 128, 0, stream>>>(stats + 256, bng + 1 * HID, bnb + 1 * HID, cs + 128, sh + 128);

    // ---- SAGE 1 ----
    csr_aggregate_kernel<true><<<aggr_blocks, 256, 0, stream>>>(
        hA, row_beg, cursor, csr_src, cs + 128, sh + 128, agg, N_NODES);
    gemm_tile_kernel<2, true, true><<<gemm_blocks, 256, 0, stream>>>(
        agg, hA, swl + 1 * HID * HID, swr + 1 * HID * HID, sbl + 1 * HID, nullptr,
        inv_deg, cs + 128, sh + 128, stats + 512, hB, N_NODES);
    bn_finalize_kernel<<<1, 128, 0, stream>>>(stats + 512, bng + 2 * HID, bnb + 2 * HID, cs + 256, sh + 256);

    // ---- pool ----
    pool_mean_kernel<<<N_GRAPHS, 128, 0, stream>>>(hB, gstart, cs + 256, sh + 256, out);
}